// Round 15
// baseline (618.594 us; speedup 1.0000x reference)
//
#include <hip/hip_runtime.h>
#include <hip/hip_cooperative_groups.h>
#include <hip/hip_bf16.h>

namespace cg = cooperative_groups;

#define N_NODES 100000
#define N_EDGES 1600000
#define N_PAD   100096
#define ZROW    N_NODES          // sentinel src: zero row in BOTH Y and Z spaces

// ---- mega-kernel geometry (256-node buckets) ----
#define MBSHIFT  8
#define MNBUCKET 391             // ceil(N/256)
#define MBCAP    4608            // records/bucket cap (mean 4092, +8 sigma)
#define MEPB     4096
#define MNSCAT   391             // ceil(E/MEPB)
#define MNG64    3126            // ceil((N+1)/32): 32-row gemm64 tiles
#define MNG32    1563            // ceil((N+1)/64): 64-row gemm32 tiles
#define MNGATH   25000           // ceil(N/4)
#define MPCAP    12544           // MBCAP + 256*31, multiple of 32
#define SMEMB    24832           // max phase smem (gemm32: 64*65*4 + 64*32*4)

// ---- fallback (R14) geometry (1024-node buckets) ----
#define BSHIFT  10
#define NBUCKET 98
#define BCAP    19456
#define EPB     4096
#define NSCAT   391
#define NGEMM1  1563
#define PCAP    34816

typedef float f32x2 __attribute__((ext_vector_type(2)));

__device__ __forceinline__ unsigned short f32_to_bf16(float f) {
    unsigned int u = __float_as_uint(f);
    unsigned int r = (u + 0x7fffu + ((u >> 16) & 1u)) >> 16;
    return (unsigned short)r;
}
__device__ __forceinline__ f32x2 up2(unsigned int p) {   // 2 bf16 -> packed f32x2
    f32x2 r;
    r.x = __uint_as_float(p << 16);
    r.y = __uint_as_float(p & 0xffff0000u);
    return r;
}

// ============================================================================
// Cooperative mega-kernel: all phases, one launch, grid.sync between.
// Eliminates ~45us of inter-dispatch gaps measured across R10-R14.
// ============================================================================
__global__ void __launch_bounds__(256) gnn_mega(
    const int* __restrict__ esrc, const int* __restrict__ edst,
    int* __restrict__ bcur, unsigned int* __restrict__ tmp,
    const float4* __restrict__ X4, const float* __restrict__ W1,
    unsigned short* __restrict__ Y, int2* __restrict__ meta,
    int* __restrict__ col, const float* __restrict__ b1,
    float* __restrict__ H, const float* __restrict__ W2,
    unsigned short* __restrict__ Z, const float* __restrict__ b2,
    const float* __restrict__ Wd, const float* __restrict__ bd,
    float* __restrict__ out) {
    __shared__ __align__(16) char smem[SMEMB];
    cg::grid_group grid = cg::this_grid();
    const int t = threadIdx.x;
    const int G = gridDim.x;

    // ---- P0: zero bucket cursors (replaces the memset launch) ----
    if (blockIdx.x == 0) { for (int i = t; i < 512; i += 256) bcur[i] = 0; }
    grid.sync();

    // ---- P1: edge scatter (vb<MNSCAT) + Y = X@W1 (32-row tiles), overlapped --
    for (int vb = blockIdx.x; vb < MNSCAT + MNG64; vb += G) {
        __syncthreads();                      // smem reuse guard across iters
        if (vb < MNSCAT) {
            int* lh = (int*)smem;             // 512-int histogram / cursor
            int e0 = vb * MEPB;
            int ecnt = min(MEPB, N_EDGES - e0);       // 4096 or 2560, %4==0
            for (int i = t; i < 512; i += 256) lh[i] = 0;
            __syncthreads();
            const int4* s4 = (const int4*)(esrc + e0);
            const int4* d4 = (const int4*)(edst + e0);
            int4 sv[4], dv[4];
            #pragma unroll
            for (int j = 0; j < 4; j++) {
                int ib = t + j * 256;
                if (ib * 4 < ecnt) {
                    sv[j] = s4[ib]; dv[j] = d4[ib];
                    atomicAdd(&lh[dv[j].x >> MBSHIFT], 1);
                    atomicAdd(&lh[dv[j].y >> MBSHIFT], 1);
                    atomicAdd(&lh[dv[j].z >> MBSHIFT], 1);
                    atomicAdd(&lh[dv[j].w >> MBSHIFT], 1);
                }
            }
            __syncthreads();
            for (int i = t; i < MNBUCKET; i += 256) {
                int c = lh[i];
                lh[i] = (c > 0) ? atomicAdd(&bcur[i], c) : 0;
            }
            __syncthreads();
            #pragma unroll
            for (int j = 0; j < 4; j++) {
                int ib = t + j * 256;
                if (ib * 4 < ecnt) {
                    int ss[4] = {sv[j].x, sv[j].y, sv[j].z, sv[j].w};
                    int dd[4] = {dv[j].x, dv[j].y, dv[j].z, dv[j].w};
                    #pragma unroll
                    for (int q = 0; q < 4; q++) {
                        int b = dd[q] >> MBSHIFT;
                        int p = atomicAdd(&lh[b], 1);
                        if (p < MBCAP)
                            tmp[(size_t)b * MBCAP + p] =
                                ((unsigned)ss[q] << MBSHIFT) | (unsigned)(dd[q] & 255);
                    }
                }
            }
        } else {
            // gemm64, 32-row tile: sx[32][65] (8320B) + sw[64*64] (16384B)
            int base = (vb - MNSCAT) * 32;
            float* sx = (float*)smem;
            float* sw = sx + 32 * 65;
            for (int i = t; i < 32 * 16; i += 256) {
                int r = i >> 4, c4 = i & 15;
                int row = base + r;
                float4 v = make_float4(0.f, 0.f, 0.f, 0.f);
                if (row < N_NODES) v = X4[(size_t)row * 16 + c4];
                sx[r * 65 + c4 * 4 + 0] = v.x; sx[r * 65 + c4 * 4 + 1] = v.y;
                sx[r * 65 + c4 * 4 + 2] = v.z; sx[r * 65 + c4 * 4 + 3] = v.w;
            }
            float4* sw4 = (float4*)sw;
            const float4* W4 = (const float4*)W1;
            for (int i = t; i < 1024; i += 256) sw4[i] = W4[i];
            __syncthreads();
            int tm = t & 15;                  // row pair: rows 2tm, 2tm+1
            int tn = t >> 4;                  // col quad: cols 4tn..4tn+3
            float acc[2][4] = {{0.f}};
            #pragma unroll 8
            for (int k = 0; k < 64; k++) {
                float4 b = sw4[k * 16 + tn];
                float a0 = sx[(2 * tm + 0) * 65 + k];
                float a1 = sx[(2 * tm + 1) * 65 + k];
                acc[0][0]=fmaf(a0,b.x,acc[0][0]); acc[0][1]=fmaf(a0,b.y,acc[0][1]);
                acc[0][2]=fmaf(a0,b.z,acc[0][2]); acc[0][3]=fmaf(a0,b.w,acc[0][3]);
                acc[1][0]=fmaf(a1,b.x,acc[1][0]); acc[1][1]=fmaf(a1,b.y,acc[1][1]);
                acc[1][2]=fmaf(a1,b.z,acc[1][2]); acc[1][3]=fmaf(a1,b.w,acc[1][3]);
            }
            #pragma unroll
            for (int i = 0; i < 2; i++) {
                int row = base + 2 * tm + i;
                if (row <= N_NODES) {         // row N: zero row for pads
                    ushort4 p;
                    p.x = f32_to_bf16(acc[i][0]); p.y = f32_to_bf16(acc[i][1]);
                    p.z = f32_to_bf16(acc[i][2]); p.w = f32_to_bf16(acc[i][3]);
                    *(ushort4*)&Y[(size_t)row * 64 + tn * 4] = p;
                }
            }
        }
    }
    grid.sync();

    // ---- P2: bucket -> padded CSR. 391 blocks, 256 nodes/bucket, 1:1 ----
    for (int vb = blockIdx.x; vb < MNBUCKET; vb += G) {
        __syncthreads();
        int* nh   = (int*)smem;               // [256]
        int* wsum = nh + 256;                 // [4]
        int m = min(bcur[vb], MBCAP);
        const unsigned int* te = tmp + (size_t)vb * MBCAP;
        nh[t] = 0;
        __syncthreads();
        for (int i = t; i < m; i += 256) atomicAdd(&nh[te[i] & 255], 1);
        __syncthreads();
        int d  = nh[t];
        int pc = (d + 31) & ~31;              // padded count (x32)
        int lane = t & 63;
        int incl = pc;
        #pragma unroll
        for (int o = 1; o < 64; o <<= 1) {
            int u = __shfl_up(incl, o);
            if (lane >= o) incl += u;
        }
        int w = t >> 6;
        if (lane == 63) wsum[w] = incl;
        __syncthreads();
        int woff = 0;
        #pragma unroll
        for (int q = 0; q < 4; q++) woff += (q < w) ? wsum[q] : 0;
        int begin = vb * MPCAP + woff + incl - pc;    // 32-aligned
        int node = (vb << MBSHIFT) + t;
        if (node < N_NODES) meta[node] = make_int2(begin, d);
        uint4 zz = make_uint4(ZROW, ZROW, ZROW, ZROW);
        uint4* cp = (uint4*)(col + begin);
        for (int q = 0; q < (pc >> 2); q++) cp[q] = zz;
        __syncthreads();
        nh[t] = begin;                        // placement cursors
        __syncthreads();
        for (int i = t; i < m; i += 256) {
            unsigned int e = te[i];
            int pos = atomicAdd(&nh[e & 255], 1);
            col[pos] = (int)(e >> MBSHIFT);
        }
    }
    grid.sync();

    // ---- P3: gather1: H[n] = relu(mean_agg(Y)[n] + b1) ----
    {
        int lane = t & 63;
        int g = lane >> 3, c = lane & 7;
        const uint4* Y4 = (const uint4*)Y;
        float4* H4 = (float4*)H;
        const float4* b1_4 = (const float4*)b1;
        float4 ba = b1_4[c * 2], bb = b1_4[c * 2 + 1];
        for (int vb = blockIdx.x; vb < MNGATH; vb += G) {
            int n = vb * 4 + (t >> 6);
            if (n >= N_NODES) continue;       // wave-uniform
            int2 md = meta[n];
            int beg = md.x, d = md.y;
            f32x2 acc[4];
            acc[0] = 0.f; acc[1] = 0.f; acc[2] = 0.f; acc[3] = 0.f;
            for (int i = 0; i < d; i += 32) {
                int s0 = col[beg + i + g];    // unconditional: pads are ZROW
                int s1 = col[beg + i + g + 8];
                int s2 = col[beg + i + g + 16];
                int s3 = col[beg + i + g + 24];
                uint4 v0 = Y4[(size_t)s0 * 8 + c];
                uint4 v1 = Y4[(size_t)s1 * 8 + c];
                uint4 v2 = Y4[(size_t)s2 * 8 + c];
                uint4 v3 = Y4[(size_t)s3 * 8 + c];
                acc[0] += (up2(v0.x) + up2(v1.x)) + (up2(v2.x) + up2(v3.x));
                acc[1] += (up2(v0.y) + up2(v1.y)) + (up2(v2.y) + up2(v3.y));
                acc[2] += (up2(v0.z) + up2(v1.z)) + (up2(v2.z) + up2(v3.z));
                acc[3] += (up2(v0.w) + up2(v1.w)) + (up2(v2.w) + up2(v3.w));
            }
            #pragma unroll
            for (int mm = 8; mm <= 32; mm <<= 1) {
                #pragma unroll
                for (int q = 0; q < 4; q++) {
                    acc[q].x += __shfl_xor(acc[q].x, mm);
                    acc[q].y += __shfl_xor(acc[q].y, mm);
                }
            }
            float inv = 1.0f / fmaxf((float)d, 1.0f);
            if (g == 0) {
                float4 o0, o1;
                o0.x = fmaxf(fmaf(acc[0].x, inv, ba.x), 0.f);
                o0.y = fmaxf(fmaf(acc[0].y, inv, ba.y), 0.f);
                o0.z = fmaxf(fmaf(acc[1].x, inv, ba.z), 0.f);
                o0.w = fmaxf(fmaf(acc[1].y, inv, ba.w), 0.f);
                o1.x = fmaxf(fmaf(acc[2].x, inv, bb.x), 0.f);
                o1.y = fmaxf(fmaf(acc[2].y, inv, bb.y), 0.f);
                o1.z = fmaxf(fmaf(acc[3].x, inv, bb.z), 0.f);
                o1.w = fmaxf(fmaf(acc[3].y, inv, bb.w), 0.f);
                H4[(size_t)n * 16 + c * 2]     = o0;
                H4[(size_t)n * 16 + c * 2 + 1] = o1;
            }
        }
    }
    grid.sync();

    // ---- P4: gemm32 64-row tiles: Z = H @ W2 (row N zeroed) ----
    for (int vb = blockIdx.x; vb < MNG32; vb += G) {
        __syncthreads();
        int base = vb * 64;
        float* sx = (float*)smem;             // [64][65] = 16640B
        float* sw = sx + 64 * 65;             // [64*32] = 8192B
        const float4* H4 = (const float4*)H;
        for (int i = t; i < 64 * 16; i += 256) {
            int r = i >> 4, c4 = i & 15;
            int row = base + r;
            float4 v = make_float4(0.f, 0.f, 0.f, 0.f);
            if (row < N_NODES) v = H4[(size_t)row * 16 + c4];
            sx[r * 65 + c4 * 4 + 0] = v.x; sx[r * 65 + c4 * 4 + 1] = v.y;
            sx[r * 65 + c4 * 4 + 2] = v.z; sx[r * 65 + c4 * 4 + 3] = v.w;
        }
        float4* sw4 = (float4*)sw;
        const float4* W4 = (const float4*)W2;
        for (int i = t; i < 512; i += 256) sw4[i] = W4[i];
        __syncthreads();
        int tm = t & 31;                      // row pair: rows 2tm, 2tm+1
        int tn = t >> 5;                      // col quad 0..7
        float acc[2][4] = {{0.f}};
        #pragma unroll 8
        for (int k = 0; k < 64; k++) {
            float4 b = sw4[k * 8 + tn];
            float a0 = sx[(2 * tm + 0) * 65 + k];
            float a1 = sx[(2 * tm + 1) * 65 + k];
            acc[0][0]=fmaf(a0,b.x,acc[0][0]); acc[0][1]=fmaf(a0,b.y,acc[0][1]);
            acc[0][2]=fmaf(a0,b.z,acc[0][2]); acc[0][3]=fmaf(a0,b.w,acc[0][3]);
            acc[1][0]=fmaf(a1,b.x,acc[1][0]); acc[1][1]=fmaf(a1,b.y,acc[1][1]);
            acc[1][2]=fmaf(a1,b.z,acc[1][2]); acc[1][3]=fmaf(a1,b.w,acc[1][3]);
        }
        #pragma unroll
        for (int i = 0; i < 2; i++) {
            int row = base + 2 * tm + i;
            if (row <= N_NODES) {             // row N: zero row for pads
                ushort4 p;
                p.x = f32_to_bf16(acc[i][0]); p.y = f32_to_bf16(acc[i][1]);
                p.z = f32_to_bf16(acc[i][2]); p.w = f32_to_bf16(acc[i][3]);
                *(ushort4*)&Z[(size_t)row * 32 + tn * 4] = p;
            }
        }
    }
    grid.sync();

    // ---- P5: gather2 -> out ----
    {
        int lane = t & 63;
        int g = lane >> 3, c = lane & 7;
        const uint2* Z2 = (const uint2*)Z;
        const float4* b2_4 = (const float4*)b2;
        float4 ba = b2_4[c];
        for (int vb = blockIdx.x; vb < MNGATH; vb += G) {
            int n = vb * 4 + (t >> 6);
            if (n >= N_NODES) continue;
            int2 md = meta[n];
            int beg = md.x, d = md.y;
            f32x2 a01 = 0.f, a23 = 0.f;
            for (int i = 0; i < d; i += 32) {
                int s0 = col[beg + i + g];
                int s1 = col[beg + i + g + 8];
                int s2 = col[beg + i + g + 16];
                int s3 = col[beg + i + g + 24];
                uint2 v0 = Z2[(size_t)s0 * 8 + c];
                uint2 v1 = Z2[(size_t)s1 * 8 + c];
                uint2 v2 = Z2[(size_t)s2 * 8 + c];
                uint2 v3 = Z2[(size_t)s3 * 8 + c];
                a01 += (up2(v0.x) + up2(v1.x)) + (up2(v2.x) + up2(v3.x));
                a23 += (up2(v0.y) + up2(v1.y)) + (up2(v2.y) + up2(v3.y));
            }
            #pragma unroll
            for (int mm = 8; mm <= 32; mm <<= 1) {
                a01.x += __shfl_xor(a01.x, mm);
                a01.y += __shfl_xor(a01.y, mm);
                a23.x += __shfl_xor(a23.x, mm);
                a23.y += __shfl_xor(a23.y, mm);
            }
            float inv = 1.0f / fmaxf((float)d, 1.0f);
            float local = fmaxf(fmaf(a01.x, inv, ba.x), 0.f)
                        + fmaxf(fmaf(a01.y, inv, ba.y), 0.f)
                        + fmaxf(fmaf(a23.x, inv, ba.z), 0.f)
                        + fmaxf(fmaf(a23.y, inv, ba.w), 0.f);
            local += __shfl_xor(local, 1);
            local += __shfl_xor(local, 2);
            local += __shfl_xor(local, 4);
            if (lane == 0) {
                float z = fmaf(local * (1.0f / 32.0f), Wd[0], bd[0]);
                out[n] = 1.0f / (1.0f + __expf(-z));
            }
        }
    }
}

// ============================================================================
// Fallback pipeline (verbatim R14 structure) — used only if cooperative
// launch is rejected. 1024-node buckets.
// ============================================================================
__global__ void __launch_bounds__(256) k1_scatter_gemm64(
    const int* __restrict__ src, const int* __restrict__ dst,
    int* __restrict__ bcur, unsigned int* __restrict__ tmp,
    const float4* __restrict__ X4, const float* __restrict__ W,
    unsigned short* __restrict__ Y, int n_edges, int M) {
    extern __shared__ char smemd[];
    int t = threadIdx.x;
    if (blockIdx.x < NSCAT) {
        int* lh = (int*)smemd;
        int e0 = blockIdx.x * EPB;
        int ecnt = min(EPB, n_edges - e0);
        if (t < 128) lh[t] = 0;
        __syncthreads();
        const int4* s4 = (const int4*)(src + e0);
        const int4* d4 = (const int4*)(dst + e0);
        int4 sv[4], dv[4];
        #pragma unroll
        for (int j = 0; j < 4; j++) {
            int ib = t + j * 256;
            if (ib * 4 < ecnt) {
                sv[j] = s4[ib]; dv[j] = d4[ib];
                atomicAdd(&lh[dv[j].x >> BSHIFT], 1);
                atomicAdd(&lh[dv[j].y >> BSHIFT], 1);
                atomicAdd(&lh[dv[j].z >> BSHIFT], 1);
                atomicAdd(&lh[dv[j].w >> BSHIFT], 1);
            }
        }
        __syncthreads();
        if (t < NBUCKET) {
            int c = lh[t];
            lh[t] = (c > 0) ? atomicAdd(&bcur[t], c) : 0;
        }
        __syncthreads();
        #pragma unroll
        for (int j = 0; j < 4; j++) {
            int ib = t + j * 256;
            if (ib * 4 < ecnt) {
                int ss[4] = {sv[j].x, sv[j].y, sv[j].z, sv[j].w};
                int dd[4] = {dv[j].x, dv[j].y, dv[j].z, dv[j].w};
                #pragma unroll
                for (int q = 0; q < 4; q++) {
                    int b = dd[q] >> BSHIFT;
                    int p = atomicAdd(&lh[b], 1);
                    if (p < BCAP)
                        tmp[(size_t)b * BCAP + p] =
                            ((unsigned)ss[q] << BSHIFT) | (unsigned)(dd[q] & 1023);
                }
            }
        }
        return;
    }
    float* sx = (float*)smemd;
    float* sw = sx + 64 * 64;
    int base = (blockIdx.x - NSCAT) * 64;
    for (int i = t; i < 64 * 16; i += 256) {
        int r = i >> 4, c4 = i & 15;
        int row = base + r;
        float4 v = make_float4(0.f, 0.f, 0.f, 0.f);
        if (row < M) v = X4[(size_t)row * 16 + c4];
        int colp = (c4 * 4 + (r & 60)) & 63;
        *(float4*)&sx[r * 64 + colp] = v;
    }
    float4* sw4 = (float4*)sw;
    const float4* W4 = (const float4*)W;
    for (int i = t; i < 64 * 16; i += 256) sw4[i] = W4[i];
    __syncthreads();
    int tm = t & 15;
    int tn = t >> 4;
    int rbase = tm * 4;
    float acc[4][4] = {{0.f}};
    #pragma unroll 8
    for (int k = 0; k < 64; k++) {
        float4 b = sw4[k * 16 + tn];
        int kk = (k + rbase) & 63;
        float a0 = sx[(rbase + 0) * 64 + kk], a1 = sx[(rbase + 1) * 64 + kk];
        float a2 = sx[(rbase + 2) * 64 + kk], a3 = sx[(rbase + 3) * 64 + kk];
        acc[0][0]=fmaf(a0,b.x,acc[0][0]); acc[0][1]=fmaf(a0,b.y,acc[0][1]);
        acc[0][2]=fmaf(a0,b.z,acc[0][2]); acc[0][3]=fmaf(a0,b.w,acc[0][3]);
        acc[1][0]=fmaf(a1,b.x,acc[1][0]); acc[1][1]=fmaf(a1,b.y,acc[1][1]);
        acc[1][2]=fmaf(a1,b.z,acc[1][2]); acc[1][3]=fmaf(a1,b.w,acc[1][3]);
        acc[2][0]=fmaf(a2,b.x,acc[2][0]); acc[2][1]=fmaf(a2,b.y,acc[2][1]);
        acc[2][2]=fmaf(a2,b.z,acc[2][2]); acc[2][3]=fmaf(a2,b.w,acc[2][3]);
        acc[3][0]=fmaf(a3,b.x,acc[3][0]); acc[3][1]=fmaf(a3,b.y,acc[3][1]);
        acc[3][2]=fmaf(a3,b.z,acc[3][2]); acc[3][3]=fmaf(a3,b.w,acc[3][3]);
    }
    #pragma unroll
    for (int i = 0; i < 4; i++) {
        int row = base + rbase + i;
        if (row <= M) {
            ushort4 p;
            p.x = f32_to_bf16(acc[i][0]); p.y = f32_to_bf16(acc[i][1]);
            p.z = f32_to_bf16(acc[i][2]); p.w = f32_to_bf16(acc[i][3]);
            *(ushort4*)&Y[(size_t)row * 64 + tn * 4] = p;
        }
    }
}

__global__ void __launch_bounds__(1024) bucket_to_csr(
    const unsigned int* __restrict__ tmp, const int* __restrict__ bcur,
    int2* __restrict__ meta, int* __restrict__ col, int n_nodes) {
    __shared__ int nh[1024];
    __shared__ int wsum[16];
    int b = blockIdx.x;
    int t = threadIdx.x;
    int m = min(bcur[b], BCAP);
    const unsigned int* te = tmp + (size_t)b * BCAP;
    nh[t] = 0;
    __syncthreads();
    unsigned int rc[16];
    #pragma unroll
    for (int j = 0; j < 16; j++) {
        int i = t + j * 1024;
        if (i < m) { rc[j] = te[i]; atomicAdd(&nh[rc[j] & 1023], 1); }
    }
    for (int i = t + 16384; i < m; i += 1024) atomicAdd(&nh[te[i] & 1023], 1);
    __syncthreads();
    int d  = nh[t];
    int pc = (d + 31) & ~31;
    int lane = t & 63;
    int incl = pc;
    #pragma unroll
    for (int o = 1; o < 64; o <<= 1) {
        int u = __shfl_up(incl, o);
        if (lane >= o) incl += u;
    }
    int w = t >> 6;
    if (lane == 63) wsum[w] = incl;
    __syncthreads();
    int woff = 0;
    #pragma unroll
    for (int q = 0; q < 16; q++) woff += (q < w) ? wsum[q] : 0;
    int begin = b * PCAP + woff + incl - pc;
    int node = (b << BSHIFT) + t;
    if (node < n_nodes) meta[node] = make_int2(begin, d);
    uint4 zz = make_uint4(ZROW, ZROW, ZROW, ZROW);
    uint4* cp = (uint4*)(col + begin);
    for (int q = 0; q < (pc >> 2); q++) cp[q] = zz;
    nh[t] = begin;
    __syncthreads();
    #pragma unroll
    for (int j = 0; j < 16; j++) {
        int i = t + j * 1024;
        if (i < m) {
            unsigned int e = rc[j];
            int pos = atomicAdd(&nh[e & 1023], 1);
            col[pos] = (int)(e >> BSHIFT);
        }
    }
    for (int i = t + 16384; i < m; i += 1024) {
        unsigned int e = te[i];
        int pos = atomicAdd(&nh[e & 1023], 1);
        col[pos] = (int)(e >> BSHIFT);
    }
}

__global__ void __launch_bounds__(256) gemm_n32(const float4* __restrict__ X4,
                                                const float* __restrict__ W,
                                                unsigned short* __restrict__ Z, int M) {
    __shared__ float sx[128][65];
    __shared__ float sw[64 * 32];
    int t = threadIdx.x;
    int base = blockIdx.x * 128;
    for (int i = t; i < 128 * 16; i += 256) {
        int r = i >> 4, c4 = i & 15;
        int row = base + r;
        float4 v = make_float4(0.f, 0.f, 0.f, 0.f);
        if (row < M) v = X4[(size_t)row * 16 + c4];
        sx[r][c4 * 4 + 0] = v.x; sx[r][c4 * 4 + 1] = v.y;
        sx[r][c4 * 4 + 2] = v.z; sx[r][c4 * 4 + 3] = v.w;
    }
    float4* sw4 = (float4*)sw;
    const float4* W4 = (const float4*)W;
    for (int i = t; i < 64 * 8; i += 256) sw4[i] = W4[i];
    __syncthreads();
    int tm = t & 31;
    int tn = t >> 5;
    float acc[4][4] = {{0.f}};
    #pragma unroll 8
    for (int k = 0; k < 64; k++) {
        float4 b = sw4[k * 8 + tn];
        float a0 = sx[tm * 4 + 0][k], a1 = sx[tm * 4 + 1][k];
        float a2 = sx[tm * 4 + 2][k], a3 = sx[tm * 4 + 3][k];
        acc[0][0]=fmaf(a0,b.x,acc[0][0]); acc[0][1]=fmaf(a0,b.y,acc[0][1]);
        acc[0][2]=fmaf(a0,b.z,acc[0][2]); acc[0][3]=fmaf(a0,b.w,acc[0][3]);
        acc[1][0]=fmaf(a1,b.x,acc[1][0]); acc[1][1]=fmaf(a1,b.y,acc[1][1]);
        acc[1][2]=fmaf(a1,b.z,acc[1][2]); acc[1][3]=fmaf(a1,b.w,acc[1][3]);
        acc[2][0]=fmaf(a2,b.x,acc[2][0]); acc[2][1]=fmaf(a2,b.y,acc[2][1]);
        acc[2][2]=fmaf(a2,b.z,acc[2][2]); acc[2][3]=fmaf(a2,b.w,acc[2][3]);
        acc[3][0]=fmaf(a3,b.x,acc[3][0]); acc[3][1]=fmaf(a3,b.y,acc[3][1]);
        acc[3][2]=fmaf(a3,b.z,acc[3][2]); acc[3][3]=fmaf(a3,b.w,acc[3][3]);
    }
    #pragma unroll
    for (int i = 0; i < 4; i++) {
        int row = base + tm * 4 + i;
        if (row <= M) {
            ushort4 p;
            p.x = f32_to_bf16(acc[i][0]); p.y = f32_to_bf16(acc[i][1]);
            p.z = f32_to_bf16(acc[i][2]); p.w = f32_to_bf16(acc[i][3]);
            *(ushort4*)&Z[(size_t)row * 32 + tn * 4] = p;
        }
    }
}

__global__ void __launch_bounds__(256) gather_relu64(
    const uint4* __restrict__ Y4, const int2* __restrict__ meta,
    const int* __restrict__ col, const float* __restrict__ b1,
    float4* __restrict__ H4, int n_nodes) {
    int n = blockIdx.x * 4 + (threadIdx.x >> 6);
    if (n >= n_nodes) return;
    int lane = threadIdx.x & 63;
    int g = lane >> 3;
    int c = lane & 7;
    int2 md = meta[n];
    int beg = md.x;
    int d = md.y;
    f32x2 acc[4];
    acc[0] = 0.f; acc[1] = 0.f; acc[2] = 0.f; acc[3] = 0.f;
    for (int i = 0; i < d; i += 32) {
        int s0 = col[beg + i + g];
        int s1 = col[beg + i + g + 8];
        int s2 = col[beg + i + g + 16];
        int s3 = col[beg + i + g + 24];
        uint4 v0 = Y4[(size_t)s0 * 8 + c];
        uint4 v1 = Y4[(size_t)s1 * 8 + c];
        uint4 v2 = Y4[(size_t)s2 * 8 + c];
        uint4 v3 = Y4[(size_t)s3 * 8 + c];
        acc[0] += (up2(v0.x) + up2(v1.x)) + (up2(v2.x) + up2(v3.x));
        acc[1] += (up2(v0.y) + up2(v1.y)) + (up2(v2.y) + up2(v3.y));
        acc[2] += (up2(v0.z) + up2(v1.z)) + (up2(v2.z) + up2(v3.z));
        acc[3] += (up2(v0.w) + up2(v1.w)) + (up2(v2.w) + up2(v3.w));
    }
    #pragma unroll
    for (int m = 8; m <= 32; m <<= 1) {
        #pragma unroll
        for (int q = 0; q < 4; q++) {
            acc[q].x += __shfl_xor(acc[q].x, m);
            acc[q].y += __shfl_xor(acc[q].y, m);
        }
    }
    float inv = 1.0f / fmaxf((float)d, 1.0f);
    const float4* b1_4 = (const float4*)b1;
    float4 ba = b1_4[c * 2], bb = b1_4[c * 2 + 1];
    if (g == 0) {
        float4 o0, o1;
        o0.x = fmaxf(fmaf(acc[0].x, inv, ba.x), 0.f);
        o0.y = fmaxf(fmaf(acc[0].y, inv, ba.y), 0.f);
        o0.z = fmaxf(fmaf(acc[1].x, inv, ba.z), 0.f);
        o0.w = fmaxf(fmaf(acc[1].y, inv, ba.w), 0.f);
        o1.x = fmaxf(fmaf(acc[2].x, inv, bb.x), 0.f);
        o1.y = fmaxf(fmaf(acc[2].y, inv, bb.y), 0.f);
        o1.z = fmaxf(fmaf(acc[3].x, inv, bb.z), 0.f);
        o1.w = fmaxf(fmaf(acc[3].y, inv, bb.w), 0.f);
        H4[(size_t)n * 16 + c * 2]     = o0;
        H4[(size_t)n * 16 + c * 2 + 1] = o1;
    }
}

__global__ void __launch_bounds__(256) gather_final32(
    const uint2* __restrict__ Z2, const int2* __restrict__ meta,
    const int* __restrict__ col, const float* __restrict__ b2,
    const float* __restrict__ Wd, const float* __restrict__ bd,
    float* __restrict__ out, int n_nodes) {
    int n = blockIdx.x * 4 + (threadIdx.x >> 6);
    if (n >= n_nodes) return;
    int lane = threadIdx.x & 63;
    int g = lane >> 3;
    int c = lane & 7;
    int2 md = meta[n];
    int beg = md.x;
    int d = md.y;
    f32x2 a01 = 0.f, a23 = 0.f;
    for (int i = 0; i < d; i += 32) {
        int s0 = col[beg + i + g];
        int s1 = col[beg + i + g + 8];
        int s2 = col[beg + i + g + 16];
        int s3 = col[beg + i + g + 24];
        uint2 v0 = Z2[(size_t)s0 * 8 + c];
        uint2 v1 = Z2[(size_t)s1 * 8 + c];
        uint2 v2 = Z2[(size_t)s2 * 8 + c];
        uint2 v3 = Z2[(size_t)s3 * 8 + c];
        a01 += (up2(v0.x) + up2(v1.x)) + (up2(v2.x) + up2(v3.x));
        a23 += (up2(v0.y) + up2(v1.y)) + (up2(v2.y) + up2(v3.y));
    }
    #pragma unroll
    for (int m = 8; m <= 32; m <<= 1) {
        a01.x += __shfl_xor(a01.x, m);
        a01.y += __shfl_xor(a01.y, m);
        a23.x += __shfl_xor(a23.x, m);
        a23.y += __shfl_xor(a23.y, m);
    }
    float inv = 1.0f / fmaxf((float)d, 1.0f);
    const float4* b2_4 = (const float4*)b2;
    float4 ba = b2_4[c];
    float local = fmaxf(fmaf(a01.x, inv, ba.x), 0.f)
                + fmaxf(fmaf(a01.y, inv, ba.y), 0.f)
                + fmaxf(fmaf(a23.x, inv, ba.z), 0.f)
                + fmaxf(fmaf(a23.y, inv, ba.w), 0.f);
    local += __shfl_xor(local, 1);
    local += __shfl_xor(local, 2);
    local += __shfl_xor(local, 4);
    if (lane == 0) {
        float z = fmaf(local * (1.0f / 32.0f), Wd[0], bd[0]);
        out[n] = 1.0f / (1.0f + __expf(-z));
    }
}

extern "C" void kernel_launch(void* const* d_in, const int* in_sizes, int n_in,
                              void* d_out, int out_size, void* d_ws, size_t ws_size,
                              hipStream_t stream) {
    const float4* x4  = (const float4*)d_in[0];
    const int*   esrc = (const int*)d_in[1];
    const int*   edst = (const int*)d_in[2];
    const float* W1   = (const float*)d_in[3];
    const float* b1   = (const float*)d_in[4];
    const float* W2   = (const float*)d_in[5];
    const float* b2   = (const float*)d_in[6];
    const float* Wd   = (const float*)d_in[7];
    const float* bd   = (const float*)d_in[8];
    float* out = (float*)d_out;

    // mega workspace layout (~65MB):
    //   bcur[512] meta[int2 x N_PAD] col[MNBUCKET*MPCAP + 64] (19.6MB)
    //   | union{ h f32[N*64] (25.6MB), tmp uint[MNBUCKET*MBCAP] (7.2MB) }
    //   | y bf16[(N+1)*64] | z2 bf16[(N+1)*32]
    int*  bcur = (int*)d_ws;
    int2* meta = (int2*)(bcur + 512);
    int*  col  = (int*)(meta + N_PAD);
    float* h   = (float*)(col + (size_t)MNBUCKET * MPCAP + 64);
    unsigned int* tmp = (unsigned int*)h;      // aliases h (dead before P3)
    unsigned short* y  = (unsigned short*)(h + (size_t)N_NODES * 64);
    unsigned short* z2 = y + (size_t)(N_NODES + 1) * 64;

    static int s_grid = 0;
    if (s_grid == 0) {
        int nb = 0;
        if (hipOccupancyMaxActiveBlocksPerMultiprocessor(
                &nb, (const void*)gnn_mega, 256, 0) != hipSuccess || nb < 1)
            nb = 4;
        s_grid = nb * 256;                     // 256 CUs on MI355X
    }

    void* args[17];
    args[0]  = (void*)&esrc; args[1]  = (void*)&edst;
    args[2]  = (void*)&bcur; args[3]  = (void*)&tmp;
    args[4]  = (void*)&x4;   args[5]  = (void*)&W1;
    args[6]  = (void*)&y;    args[7]  = (void*)&meta;
    args[8]  = (void*)&col;  args[9]  = (void*)&b1;
    args[10] = (void*)&h;    args[11] = (void*)&W2;
    args[12] = (void*)&z2;   args[13] = (void*)&b2;
    args[14] = (void*)&Wd;   args[15] = (void*)&bd;
    args[16] = (void*)&out;

    hipError_t err = hipLaunchCooperativeKernel(
        (void*)gnn_mega, dim3(s_grid), dim3(256), args, 0, stream);

    if (err != hipSuccess) {
        // -------- fallback: R14 multi-kernel pipeline (1024-node buckets) ----
        int*  fbcur = (int*)d_ws;
        int2* fmeta = (int2*)(fbcur + 128);
        int*  fcol  = (int*)(fmeta + N_PAD);
        float* fh   = (float*)(fcol + (size_t)NBUCKET * PCAP + 1024);
        unsigned int* ftmp = (unsigned int*)fh;
        unsigned short* fy  = (unsigned short*)(fh + (size_t)N_NODES * 64);
        unsigned short* fz2 = fy + (size_t)(N_NODES + 1) * 64;

        hipMemsetAsync((void*)fbcur, 0, 128 * sizeof(int), stream);
        k1_scatter_gemm64<<<NSCAT + NGEMM1, 256, 32768, stream>>>(
            esrc, edst, fbcur, ftmp, x4, W1, fy, N_EDGES, N_NODES);
        bucket_to_csr<<<NBUCKET, 1024, 0, stream>>>(ftmp, fbcur, fmeta, fcol, N_NODES);
        gather_relu64<<<(N_NODES + 3) / 4, 256, 0, stream>>>(
            (const uint4*)fy, fmeta, fcol, b1, (float4*)fh, N_NODES);
        gemm_n32<<<(N_NODES + 127) / 128, 256, 0, stream>>>(
            (const float4*)fh, W2, fz2, N_NODES);
        gather_final32<<<(N_NODES + 3) / 4, 256, 0, stream>>>(
            (const uint2*)fz2, fmeta, fcol, b2, Wd, bd, out, N_NODES);
    }
}

// Round 16
// 236.622 us; speedup vs baseline: 2.6143x; 2.6143x over previous
//
#include <hip/hip_runtime.h>
#include <hip/hip_bf16.h>

#define N_NODES 100000
#define N_EDGES 1600000
#define N_PAD   100096          // N rounded up to 128
#define BSHIFT  10              // 1024 nodes per bucket
#define NBUCKET 98              // ceil(N_NODES / 1024)
#define BCAP    19456           // per-bucket record capacity (mean 16327, +8 sigma)
#define EPB     4096            // edges per scatter block
#define NSCAT   391             // scatter blocks = ceil(E / EPB)
#define NGEMM1  1563            // gemm64 blocks = ceil((N+1)/64)
#define PCAP    34816           // per-bucket PADDED col capacity (mean 32775)
#define ZROW    N_NODES         // sentinel src: zero row in BOTH Y and Z spaces

__device__ __forceinline__ unsigned short f32_to_bf16(float f) {
    unsigned int u = __float_as_uint(f);
    unsigned int r = (u + 0x7fffu + ((u >> 16) & 1u)) >> 16;
    return (unsigned short)r;
}
__device__ __forceinline__ float bf16_lo(unsigned int p) {   // low 16 bits
    return __uint_as_float(p << 16);
}
__device__ __forceinline__ float bf16_hi(unsigned int p) {   // high 16 bits
    return __uint_as_float(p & 0xffff0000u);
}

// ---------- K1: fused scatter + gemm_n64 (independent work, one launch) ------
// Blocks [0,NSCAT): bucket scatter, edges loaded as int4 (4/load).
// Blocks [NSCAT,..): Y[M+1,64] = X @ W1 (bf16 out, row M zeroed via <=M guard).
// R12 proved un-fusing costs ~11us (same-stream kernels serialize);
// R15 proved the cooperative mega-kernel costs 3x (occupancy + lost overlap).
__global__ void __launch_bounds__(256) k1_scatter_gemm64(
    const int* __restrict__ src, const int* __restrict__ dst,
    int* __restrict__ bcur, unsigned int* __restrict__ tmp,
    const float4* __restrict__ X4, const float* __restrict__ W,
    unsigned short* __restrict__ Y, int n_edges, int M) {
    extern __shared__ char smem[];
    int t = threadIdx.x;
    if (blockIdx.x < NSCAT) {
        int* lh = (int*)smem;            // 128-entry histogram / cursor
        int e0 = blockIdx.x * EPB;
        int ecnt = min(EPB, n_edges - e0);          // 4096 or 2560 (both %4==0)
        if (t < 128) lh[t] = 0;
        __syncthreads();
        const int4* s4 = (const int4*)(src + e0);   // e0 %4==0 -> 16B aligned
        const int4* d4 = (const int4*)(dst + e0);
        int4 sv[4], dv[4];
        #pragma unroll
        for (int j = 0; j < 4; j++) {
            int ib = t + j * 256;                   // int4 slot, covers 4096 edges
            if (ib * 4 < ecnt) {
                sv[j] = s4[ib];
                dv[j] = d4[ib];
                atomicAdd(&lh[dv[j].x >> BSHIFT], 1);
                atomicAdd(&lh[dv[j].y >> BSHIFT], 1);
                atomicAdd(&lh[dv[j].z >> BSHIFT], 1);
                atomicAdd(&lh[dv[j].w >> BSHIFT], 1);
            }
        }
        __syncthreads();
        if (t < NBUCKET) {
            int c = lh[t];
            lh[t] = (c > 0) ? atomicAdd(&bcur[t], c) : 0;
        }
        __syncthreads();
        #pragma unroll
        for (int j = 0; j < 4; j++) {
            int ib = t + j * 256;
            if (ib * 4 < ecnt) {
                int ss[4] = {sv[j].x, sv[j].y, sv[j].z, sv[j].w};
                int dd[4] = {dv[j].x, dv[j].y, dv[j].z, dv[j].w};
                #pragma unroll
                for (int q = 0; q < 4; q++) {
                    int b = dd[q] >> BSHIFT;
                    int p = atomicAdd(&lh[b], 1);
                    if (p < BCAP)
                        tmp[(size_t)b * BCAP + p] =
                            ((unsigned)ss[q] << BSHIFT) | (unsigned)(dd[q] & 1023);
                }
            }
        }
        return;
    }
    // ---- gemm64 part ----
    float* sx = (float*)smem;            // [64][65]
    float* sw = sx + 64 * 65;            // [64*64]
    int base = (blockIdx.x - NSCAT) * 64;
    for (int i = t; i < 64 * 16; i += 256) {
        int r = i >> 4, c4 = i & 15;
        int row = base + r;
        float4 v = make_float4(0.f, 0.f, 0.f, 0.f);
        if (row < M) v = X4[(size_t)row * 16 + c4];
        sx[r * 65 + c4 * 4 + 0] = v.x; sx[r * 65 + c4 * 4 + 1] = v.y;
        sx[r * 65 + c4 * 4 + 2] = v.z; sx[r * 65 + c4 * 4 + 3] = v.w;
    }
    float4* sw4 = (float4*)sw;
    const float4* W4 = (const float4*)W;
    for (int i = t; i < 64 * 16; i += 256) sw4[i] = W4[i];
    __syncthreads();

    int tm = t & 15;
    int tn = t >> 4;
    float acc[4][4] = {{0.f}};
    #pragma unroll 8
    for (int k = 0; k < 64; k++) {
        float4 b = sw4[k * 16 + tn];
        float a0 = sx[(tm * 4 + 0) * 65 + k], a1 = sx[(tm * 4 + 1) * 65 + k];
        float a2 = sx[(tm * 4 + 2) * 65 + k], a3 = sx[(tm * 4 + 3) * 65 + k];
        acc[0][0] = fmaf(a0, b.x, acc[0][0]); acc[0][1] = fmaf(a0, b.y, acc[0][1]);
        acc[0][2] = fmaf(a0, b.z, acc[0][2]); acc[0][3] = fmaf(a0, b.w, acc[0][3]);
        acc[1][0] = fmaf(a1, b.x, acc[1][0]); acc[1][1] = fmaf(a1, b.y, acc[1][1]);
        acc[1][2] = fmaf(a1, b.z, acc[1][2]); acc[1][3] = fmaf(a1, b.w, acc[1][3]);
        acc[2][0] = fmaf(a2, b.x, acc[2][0]); acc[2][1] = fmaf(a2, b.y, acc[2][1]);
        acc[2][2] = fmaf(a2, b.z, acc[2][2]); acc[2][3] = fmaf(a2, b.w, acc[2][3]);
        acc[3][0] = fmaf(a3, b.x, acc[3][0]); acc[3][1] = fmaf(a3, b.y, acc[3][1]);
        acc[3][2] = fmaf(a3, b.z, acc[3][2]); acc[3][3] = fmaf(a3, b.w, acc[3][3]);
    }
    #pragma unroll
    for (int i = 0; i < 4; i++) {
        int row = base + tm * 4 + i;
        if (row <= M) {     // row == M: zero row (acc==0), feeds gather pads
            ushort4 p;
            p.x = f32_to_bf16(acc[i][0]); p.y = f32_to_bf16(acc[i][1]);
            p.z = f32_to_bf16(acc[i][2]); p.w = f32_to_bf16(acc[i][3]);
            *(ushort4*)&Y[(size_t)row * 64 + tn * 4] = p;
        }
    }
}

// ---------- per-bucket -> PADDED CSR (node lists padded to x32 with ZROW) ----
// Wave-shfl scan (4 barriers vs 40), records register-cached across passes
// (16/thread, static indices), pad fill via aligned uint4 full-fill of
// [begin, begin+pc) which placement then overwrites.
__global__ void __launch_bounds__(1024) bucket_to_csr(
    const unsigned int* __restrict__ tmp, const int* __restrict__ bcur,
    int2* __restrict__ meta, int* __restrict__ col, int n_nodes) {
    __shared__ int nh[1024];
    __shared__ int wsum[16];
    int b = blockIdx.x;
    int t = threadIdx.x;
    int m = min(bcur[b], BCAP);
    const unsigned int* te = tmp + (size_t)b * BCAP;
    nh[t] = 0;
    __syncthreads();
    // pass 1: histogram, caching the records in registers (static indices)
    unsigned int rc[16];
    #pragma unroll
    for (int j = 0; j < 16; j++) {
        int i = t + j * 1024;
        if (i < m) {
            rc[j] = te[i];
            atomicAdd(&nh[rc[j] & 1023], 1);
        }
    }
    for (int i = t + 16384; i < m; i += 1024)       // rare tail (m > 16384)
        atomicAdd(&nh[te[i] & 1023], 1);
    __syncthreads();
    // padded-count exclusive scan: wave shfl scan + 16-entry cross-wave scan
    int d  = nh[t];
    int pc = (d + 31) & ~31;                        // padded count (x32)
    int lane = t & 63;
    int incl = pc;
    #pragma unroll
    for (int o = 1; o < 64; o <<= 1) {
        int u = __shfl_up(incl, o);
        if (lane >= o) incl += u;
    }
    int w = t >> 6;                                 // wave 0..15
    if (lane == 63) wsum[w] = incl;
    __syncthreads();
    int woff = 0;
    #pragma unroll
    for (int q = 0; q < 16; q++) woff += (q < w) ? wsum[q] : 0;
    int begin = b * PCAP + woff + incl - pc;        // exclusive prefix, 32-aligned
    int node = (b << BSHIFT) + t;
    if (node < n_nodes) meta[node] = make_int2(begin, d);
    // vectorized fill of the whole padded list with ZROW (placement overwrites)
    uint4 zz = make_uint4(ZROW, ZROW, ZROW, ZROW);
    uint4* cp = (uint4*)(col + begin);              // begin x32 -> 16B aligned
    for (int q = 0; q < (pc >> 2); q++) cp[q] = zz;
    nh[t] = begin;                                  // repurpose as cursor
    __syncthreads();
    // pass 2: placement from the register cache (no tmp re-read)
    #pragma unroll
    for (int j = 0; j < 16; j++) {
        int i = t + j * 1024;
        if (i < m) {
            unsigned int e = rc[j];
            int pos = atomicAdd(&nh[e & 1023], 1);
            col[pos] = (int)(e >> BSHIFT);
        }
    }
    for (int i = t + 16384; i < m; i += 1024) {
        unsigned int e = te[i];
        int pos = atomicAdd(&nh[e & 1023], 1);
        col[pos] = (int)(e >> BSHIFT);
    }
}

// ---------- dense GEMM: Z[M+1,32] = H[M,64] @ W[64,32] (row M zeroed) --------
__global__ void __launch_bounds__(256) gemm_n32(const float4* __restrict__ X4,
                                                const float* __restrict__ W,
                                                unsigned short* __restrict__ Z, int M) {
    __shared__ float sx[128][65];
    __shared__ float sw[64 * 32];
    int t = threadIdx.x;
    int base = blockIdx.x * 128;
    for (int i = t; i < 128 * 16; i += 256) {
        int r = i >> 4, c4 = i & 15;
        int row = base + r;
        float4 v = make_float4(0.f, 0.f, 0.f, 0.f);
        if (row < M) v = X4[(size_t)row * 16 + c4];
        sx[r][c4 * 4 + 0] = v.x; sx[r][c4 * 4 + 1] = v.y;
        sx[r][c4 * 4 + 2] = v.z; sx[r][c4 * 4 + 3] = v.w;
    }
    float4* sw4 = (float4*)sw;
    const float4* W4 = (const float4*)W;
    for (int i = t; i < 64 * 8; i += 256) sw4[i] = W4[i];
    __syncthreads();

    int tm = t & 31;
    int tn = t >> 5;
    float acc[4][4] = {{0.f}};
    #pragma unroll 8
    for (int k = 0; k < 64; k++) {
        float4 b = sw4[k * 8 + tn];
        float a0 = sx[tm * 4 + 0][k], a1 = sx[tm * 4 + 1][k];
        float a2 = sx[tm * 4 + 2][k], a3 = sx[tm * 4 + 3][k];
        acc[0][0] = fmaf(a0, b.x, acc[0][0]); acc[0][1] = fmaf(a0, b.y, acc[0][1]);
        acc[0][2] = fmaf(a0, b.z, acc[0][2]); acc[0][3] = fmaf(a0, b.w, acc[0][3]);
        acc[1][0] = fmaf(a1, b.x, acc[1][0]); acc[1][1] = fmaf(a1, b.y, acc[1][1]);
        acc[1][2] = fmaf(a1, b.z, acc[1][2]); acc[1][3] = fmaf(a1, b.w, acc[1][3]);
        acc[2][0] = fmaf(a2, b.x, acc[2][0]); acc[2][1] = fmaf(a2, b.y, acc[2][1]);
        acc[2][2] = fmaf(a2, b.z, acc[2][2]); acc[2][3] = fmaf(a2, b.w, acc[2][3]);
        acc[3][0] = fmaf(a3, b.x, acc[3][0]); acc[3][1] = fmaf(a3, b.y, acc[3][1]);
        acc[3][2] = fmaf(a3, b.z, acc[3][2]); acc[3][3] = fmaf(a3, b.w, acc[3][3]);
    }
    #pragma unroll
    for (int i = 0; i < 4; i++) {
        int row = base + tm * 4 + i;
        if (row <= M) {     // row == M: zero row for gather2 pads
            ushort4 p;
            p.x = f32_to_bf16(acc[i][0]); p.y = f32_to_bf16(acc[i][1]);
            p.z = f32_to_bf16(acc[i][2]); p.w = f32_to_bf16(acc[i][3]);
            *(ushort4*)&Z[(size_t)row * 32 + tn * 4] = p;
        }
    }
}

// ---------- gather1: h[n] = relu(mean_{s in N(n)} y[s] + b1) -----------------
// col is padded to x32 with ZROW -> NO clamp/select per slot: pure load chain.
// (R8 version. R9's W2-register fusion regressed 3x — do not re-fuse.)
__global__ void __launch_bounds__(256) gather_relu64(
    const uint4* __restrict__ Y4, const int2* __restrict__ meta,
    const int* __restrict__ col, const float* __restrict__ b1,
    float4* __restrict__ H4, int n_nodes) {
    int n = blockIdx.x * 4 + (threadIdx.x >> 6);
    if (n >= n_nodes) return;
    int lane = threadIdx.x & 63;
    int g = lane >> 3;          // edge subgroup 0..7
    int c = lane & 7;           // 8-feature chunk 0..7
    int2 md = meta[n];
    int beg = md.x;
    int d = md.y;

    float acc[8] = {0.f, 0.f, 0.f, 0.f, 0.f, 0.f, 0.f, 0.f};
    for (int i = 0; i < d; i += 32) {
        int s0 = col[beg + i + g];          // unconditional: pads are ZROW
        int s1 = col[beg + i + g + 8];
        int s2 = col[beg + i + g + 16];
        int s3 = col[beg + i + g + 24];
        uint4 v0 = Y4[(size_t)s0 * 8 + c];
        uint4 v1 = Y4[(size_t)s1 * 8 + c];
        uint4 v2 = Y4[(size_t)s2 * 8 + c];
        uint4 v3 = Y4[(size_t)s3 * 8 + c];
        acc[0] += (bf16_lo(v0.x) + bf16_lo(v1.x)) + (bf16_lo(v2.x) + bf16_lo(v3.x));
        acc[1] += (bf16_hi(v0.x) + bf16_hi(v1.x)) + (bf16_hi(v2.x) + bf16_hi(v3.x));
        acc[2] += (bf16_lo(v0.y) + bf16_lo(v1.y)) + (bf16_lo(v2.y) + bf16_lo(v3.y));
        acc[3] += (bf16_hi(v0.y) + bf16_hi(v1.y)) + (bf16_hi(v2.y) + bf16_hi(v3.y));
        acc[4] += (bf16_lo(v0.z) + bf16_lo(v1.z)) + (bf16_lo(v2.z) + bf16_lo(v3.z));
        acc[5] += (bf16_hi(v0.z) + bf16_hi(v1.z)) + (bf16_hi(v2.z) + bf16_hi(v3.z));
        acc[6] += (bf16_lo(v0.w) + bf16_lo(v1.w)) + (bf16_lo(v2.w) + bf16_lo(v3.w));
        acc[7] += (bf16_hi(v0.w) + bf16_hi(v1.w)) + (bf16_hi(v2.w) + bf16_hi(v3.w));
    }
    #pragma unroll
    for (int m = 8; m <= 32; m <<= 1) {
        #pragma unroll
        for (int q = 0; q < 8; q++) acc[q] += __shfl_xor(acc[q], m);
    }
    float inv = 1.0f / fmaxf((float)d, 1.0f);
    const float4* b1_4 = (const float4*)b1;
    float4 ba = b1_4[c * 2], bb = b1_4[c * 2 + 1];
    if (g == 0) {
        float4 o0, o1;
        o0.x = fmaxf(fmaf(acc[0], inv, ba.x), 0.f);
        o0.y = fmaxf(fmaf(acc[1], inv, ba.y), 0.f);
        o0.z = fmaxf(fmaf(acc[2], inv, ba.z), 0.f);
        o0.w = fmaxf(fmaf(acc[3], inv, ba.w), 0.f);
        o1.x = fmaxf(fmaf(acc[4], inv, bb.x), 0.f);
        o1.y = fmaxf(fmaf(acc[5], inv, bb.y), 0.f);
        o1.z = fmaxf(fmaf(acc[6], inv, bb.z), 0.f);
        o1.w = fmaxf(fmaf(acc[7], inv, bb.w), 0.f);
        H4[(size_t)n * 16 + c * 2]     = o0;
        H4[(size_t)n * 16 + c * 2 + 1] = o1;
    }
}

// ---------- gather2: out[n] = sigmoid(mean_f(relu(mean_agg(z2)[n]+b2))*Wd+bd) --
// c in 0..7 (uint2 loads), g in 0..7 -> epilogue is 12+3 shfl.
__global__ void __launch_bounds__(256) gather_final32(
    const uint2* __restrict__ Z2, const int2* __restrict__ meta,
    const int* __restrict__ col, const float* __restrict__ b2,
    const float* __restrict__ Wd, const float* __restrict__ bd,
    float* __restrict__ out, int n_nodes) {
    int n = blockIdx.x * 4 + (threadIdx.x >> 6);
    if (n >= n_nodes) return;
    int lane = threadIdx.x & 63;
    int g = lane >> 3;          // edge subgroup 0..7
    int c = lane & 7;           // 4-feature chunk 0..7
    int2 md = meta[n];
    int beg = md.x;
    int d = md.y;

    float a0 = 0.f, a1 = 0.f, a2 = 0.f, a3 = 0.f;
    for (int i = 0; i < d; i += 32) {
        int s0 = col[beg + i + g];          // unconditional: pads are ZROW
        int s1 = col[beg + i + g + 8];
        int s2 = col[beg + i + g + 16];
        int s3 = col[beg + i + g + 24];
        uint2 v0 = Z2[(size_t)s0 * 8 + c];
        uint2 v1 = Z2[(size_t)s1 * 8 + c];
        uint2 v2 = Z2[(size_t)s2 * 8 + c];
        uint2 v3 = Z2[(size_t)s3 * 8 + c];
        a0 += (bf16_lo(v0.x) + bf16_lo(v1.x)) + (bf16_lo(v2.x) + bf16_lo(v3.x));
        a1 += (bf16_hi(v0.x) + bf16_hi(v1.x)) + (bf16_hi(v2.x) + bf16_hi(v3.x));
        a2 += (bf16_lo(v0.y) + bf16_lo(v1.y)) + (bf16_lo(v2.y) + bf16_lo(v3.y));
        a3 += (bf16_hi(v0.y) + bf16_hi(v1.y)) + (bf16_hi(v2.y) + bf16_hi(v3.y));
    }
    #pragma unroll
    for (int m = 8; m <= 32; m <<= 1) {
        a0 += __shfl_xor(a0, m);
        a1 += __shfl_xor(a1, m);
        a2 += __shfl_xor(a2, m);
        a3 += __shfl_xor(a3, m);
    }
    float inv = 1.0f / fmaxf((float)d, 1.0f);
    const float4* b2_4 = (const float4*)b2;
    float4 ba = b2_4[c];                    // b2[4c..4c+3]
    float local = fmaxf(fmaf(a0, inv, ba.x), 0.f)
                + fmaxf(fmaf(a1, inv, ba.y), 0.f)
                + fmaxf(fmaf(a2, inv, ba.z), 0.f)
                + fmaxf(fmaf(a3, inv, ba.w), 0.f);
    local += __shfl_xor(local, 1);
    local += __shfl_xor(local, 2);
    local += __shfl_xor(local, 4);
    if (lane == 0) {
        float z = fmaf(local * (1.0f / 32.0f), Wd[0], bd[0]);
        out[n] = 1.0f / (1.0f + __expf(-z));
    }
}

extern "C" void kernel_launch(void* const* d_in, const int* in_sizes, int n_in,
                              void* d_out, int out_size, void* d_ws, size_t ws_size,
                              hipStream_t stream) {
    const float* x    = (const float*)d_in[0];   // [N,64]
    const int*   esrc = (const int*)d_in[1];     // [E]
    const int*   edst = (const int*)d_in[2];     // [E]
    const float* W1   = (const float*)d_in[3];   // [64,64]
    const float* b1   = (const float*)d_in[4];   // [64]
    const float* W2   = (const float*)d_in[5];   // [64,32]
    const float* b2   = (const float*)d_in[6];   // [32]
    const float* Wd   = (const float*)d_in[7];   // [1,1]
    const float* bd   = (const float*)d_in[8];   // [1]
    float* out = (float*)d_out;                  // [N,1]

    // workspace (~59.3 MB), R8/R10 layout:
    //   bcur[128] meta[int2 x N_PAD] col[NBUCKET*PCAP + 1024] (13.7MB)
    //   | union{ h f32[N*64] (25.6MB), tmp uint[NBUCKET*BCAP] (7.6MB) }
    //   | y bf16[(N+1)*64] (12.8MB, row N = zero row)
    //   | z2 bf16[(N+1)*32] (6.4MB, row N = zero row)
    int*  bcur = (int*)d_ws;
    int2* meta = (int2*)(bcur + 128);
    int*  col  = (int*)(meta + N_PAD);
    float* h   = (float*)(col + (size_t)NBUCKET * PCAP + 1024);
    unsigned int* tmp = (unsigned int*)h;        // aliases h (dead until gather1)
    unsigned short* y  = (unsigned short*)(h + (size_t)N_NODES * 64);
    unsigned short* z2 = y + (size_t)(N_NODES + 1) * 64;

    hipMemsetAsync((void*)bcur, 0, 128 * sizeof(int), stream);

    // K1: scatter (391 blocks, int4 edge loads) + y = x@W1 incl. zero row
    k1_scatter_gemm64<<<NSCAT + NGEMM1, 256, 33024, stream>>>(
        esrc, edst, bcur, tmp, (const float4*)x, W1, y, N_EDGES, N_NODES);
    // padded CSR (x32 node lists, ZROW sentinels) — barrier-light version
    bucket_to_csr<<<NBUCKET, 1024, 0, stream>>>(tmp, bcur, meta, col, N_NODES);
    // h = relu(mean_agg(y) + b1)   (h overwrites tmp, which is dead now)
    gather_relu64<<<(N_NODES + 3) / 4, 256, 0, stream>>>(
        (const uint4*)y, meta, col, b1, (float4*)h, N_NODES);
    // z2 = h @ W2 incl. zero row
    gemm_n32<<<(N_NODES + 127) / 128, 256, 0, stream>>>((const float4*)h, W2, z2, N_NODES);
    // out = sigmoid(mean(relu(mean_agg(z2) + b2)) * Wd + bd)
    gather_final32<<<(N_NODES + 3) / 4, 256, 0, stream>>>(
        (const uint2*)z2, meta, col, b2, Wd, bd, out, N_NODES);
}